// Round 10
// baseline (624.034 us; speedup 1.0000x reference)
//
#include <hip/hip_runtime.h>
#include <hip/hip_fp16.h>

// GAT 2-layer GNN. CSR-gather formulation.
// R9: multi-pass bucketed scatter. 2048 co-resident blocks x 16 dst-range
// passes -> writes per phase confined to ~1.6MB CSR region so 64B lines fill
// before eviction (attacks the 3.2M-random-line writeback cost measured in R8).
// (Resubmit — R9 bench hit GPUAcquisitionTimeout.)

#define NN 100000
#define EE 3200000
#define SLOPE 0.2f
#define SB 1024
#define SNB ((NN + SB - 1) / SB)   // 98 blocks
#define KP 16                      // scatter dst-range passes
#define SGRID 2048                 // co-resident scatter grid (256 CU x 8 blocks)

// ---- tiny weight folds: w4_1[4], w4_2[4], vs1[3], vd1[3] (14 floats) ----
__global__ void k_small(const float* __restrict__ We1, const float* __restrict__ ae1,
                        const float* __restrict__ We2, const float* __restrict__ ae2,
                        const float* __restrict__ W1, const float* __restrict__ as1,
                        const float* __restrict__ ad1, float* __restrict__ sml) {
    int t = threadIdx.x;
    if (t < 4) {
        float s = 0.f;
        for (int k = 0; k < 32; k++) s += We1[t * 32 + k] * ae1[k];
        sml[t] = s;
    } else if (t < 8) {
        float s = 0.f;
        for (int k = 0; k < 32; k++) s += We2[(t - 4) * 32 + k] * ae2[k];
        sml[t] = s;
    } else if (t < 11) {
        int i = t - 8;
        float s = 0.f;
        for (int k = 0; k < 32; k++) s += W1[i * 32 + k] * as1[k];
        sml[t] = s;
    } else if (t < 14) {
        int i = t - 11;
        float s = 0.f;
        for (int k = 0; k < 32; k++) s += W1[i * 32 + k] * ad1[k];
        sml[t] = s;
    }
}

__global__ void k_deg(const int* __restrict__ ei, int* __restrict__ deg) {
    int e = blockIdx.x * blockDim.x + threadIdx.x;
    if (e >= EE) return;
    atomicAdd(&deg[ei[EE + e]], 1);
}

// stage 1: per-block LDS scan
__global__ void k_scan1(const int* __restrict__ deg, int* __restrict__ loc,
                        int* __restrict__ bsum) {
    __shared__ int sd[SB];
    int t = threadIdx.x;
    int i = blockIdx.x * SB + t;
    int v = (i < NN) ? deg[i] : 0;
    sd[t] = v;
    __syncthreads();
    for (int o = 1; o < SB; o <<= 1) {
        int u = (t >= o) ? sd[t - o] : 0;
        __syncthreads();
        sd[t] += u;
        __syncthreads();
    }
    if (i < NN) loc[i] = sd[t] - v;
    if (t == SB - 1) bsum[blockIdx.x] = sd[t];
}

// stage 2: single small block scans the block sums in place
__global__ void k_scan2(int* __restrict__ bsum) {
    __shared__ int sd[128];
    int t = threadIdx.x;
    int v = (t < SNB) ? bsum[t] : 0;
    sd[t] = v;
    __syncthreads();
    for (int o = 1; o < 128; o <<= 1) {
        int u = (t >= o) ? sd[t - o] : 0;
        __syncthreads();
        sd[t] += u;
        __syncthreads();
    }
    if (t < SNB) bsum[t] = sd[t] - v;
}

// stage 3: rp/cur = combined prefix; fused layer-1 logit dots hs/hd
__global__ void k_scan3(const int* __restrict__ loc, const int* __restrict__ bsum,
                        int* __restrict__ rp, int* __restrict__ cur,
                        const float* __restrict__ x, const float* __restrict__ sml,
                        float* __restrict__ hs, float* __restrict__ hd) {
    int i = blockIdx.x * blockDim.x + threadIdx.x;
    if (i > NN) return;
    if (i == NN) { rp[NN] = EE; return; }
    int p = loc[i] + bsum[i / SB];
    rp[i] = p;
    cur[i] = p;
    float x0 = x[i * 3], x1 = x[i * 3 + 1], x2 = x[i * 3 + 2];
    hs[i] = x0 * sml[8] + x1 * sml[9] + x2 * sml[10];
    hd[i] = x0 * sml[11] + x1 * sml[12] + x2 * sml[13];
}

// scatter: 16 dst-range passes over each block's private edge chunk.
// All SGRID blocks co-resident -> phase-p writes confined to ~1/16 of the
// CSR region -> 64B lines fill before eviction.
__global__ void __launch_bounds__(256, 8) k_scatter(
    const int* __restrict__ ei, const float* __restrict__ ea,
    const float* __restrict__ sml, int* __restrict__ cur,
    int2* __restrict__ cpack) {
    const int C = (EE + SGRID - 1) / SGRID;
    int base = blockIdx.x * C;
    int lim = min(base + C, EE);
    float s0 = sml[0], s1 = sml[1], s2 = sml[2], s3 = sml[3];
    float s4 = sml[4], s5 = sml[5], s6 = sml[6], s7 = sml[7];
    for (int pass = 0; pass < KP; ++pass) {
        int lo = (int)(((long long)pass * NN) / KP);
        int hi = (int)(((long long)(pass + 1) * NN) / KP);
        for (int e = base + (int)threadIdx.x; e < lim; e += blockDim.x) {
            int d = ei[EE + e];
            if (d < lo || d >= hi) continue;
            int s = ei[e];
            float4 a = reinterpret_cast<const float4*>(ea)[e];
            float e1 = a.x * s0 + a.y * s1 + a.z * s2 + a.w * s3;
            float e2 = a.x * s4 + a.y * s5 + a.z * s6 + a.w * s7;
            __half2 hv = __floats2half2_rn(e1, e2);
            int2 rec;
            rec.x = s;
            rec.y = *reinterpret_cast<int*>(&hv);
            int p = atomicAdd(&cur[d], 1);
            cpack[p] = rec;
        }
        __syncthreads();
    }
}

// h2 = xbuf @ W2 (N x 32 -> N x 32) + dots with a_src2/a_dst2
__global__ void k_h2(const float* __restrict__ x2, const float* __restrict__ W,
                     const float* __restrict__ as_, const float* __restrict__ ad_,
                     float* __restrict__ h, float* __restrict__ hs, float* __restrict__ hd) {
    __shared__ float sW[1024], sa[32], sdv[32];
    int t = threadIdx.x;
    for (int i = t; i < 1024; i += blockDim.x) sW[i] = W[i];
    if (t < 32) { sa[t] = as_[t]; sdv[t] = ad_[t]; }
    __syncthreads();
    int n = blockIdx.x * blockDim.x + t;
    if (n >= NN) return;
    float xl[32];
    const float4* xp = reinterpret_cast<const float4*>(x2 + (size_t)n * 32);
#pragma unroll
    for (int q = 0; q < 8; q++) {
        float4 v = xp[q];
        xl[q * 4 + 0] = v.x; xl[q * 4 + 1] = v.y; xl[q * 4 + 2] = v.z; xl[q * 4 + 3] = v.w;
    }
    float ss = 0.f, dd = 0.f;
    float* hp = h + (size_t)n * 32;
    for (int q = 0; q < 8; q++) {
        float4 o;
        float* op = (float*)&o;
        for (int j = 0; j < 4; j++) {
            int k = q * 4 + j;
            float acc = 0.f;
#pragma unroll
            for (int i = 0; i < 32; i++) acc += xl[i] * sW[i * 32 + k];
            op[j] = acc;
            ss += acc * sa[k];
            dd += acc * sdv[k];
        }
        reinterpret_cast<float4*>(hp)[q] = o;
    }
    hs[n] = ss; hd[n] = dd;
}

// one wave per node: softmax + aggregation. LAYER=0: recompute h1[src] from x;
// LAYER=1: read h[src], fuse final linear(32->1)+relu.
template <int LAYER>
__global__ void __launch_bounds__(256) k_gather(
    const int* __restrict__ rp, const int2* __restrict__ cpack,
    const float* __restrict__ hsrc,
    const float* __restrict__ W1, const float* __restrict__ hs,
    const float* __restrict__ hd, const float* __restrict__ bias,
    const float* __restrict__ Wl, const float* __restrict__ bl,
    float* __restrict__ out) {
    __shared__ float sW[96];
    if (LAYER == 0) {
        if (threadIdx.x < 96) sW[threadIdx.x] = W1[threadIdx.x];
        __syncthreads();
    }
    int wid = (blockIdx.x * blockDim.x + threadIdx.x) >> 6;
    int lane = threadIdx.x & 63;
    if (wid >= NN) return;
    int n = wid;
    int beg = rp[n], end = rp[n + 1];
    int deg = end - beg;
    float hdn = hd[n];

    // pass 1: max logit + sum of eaw (for self-loop mean attr)
    float mymax = -1e30f, mysum = 0.f;
    for (int j = beg + lane; j < end; j += 64) {
        int2 cp = cpack[j];
        __half2 hv = *reinterpret_cast<__half2*>(&cp.y);
        float2 ew = __half22float2(hv);
        float eaw = (LAYER == 0) ? ew.x : ew.y;
        float l = hs[cp.x] + hdn + eaw;
        l = (l >= 0.f) ? l : SLOPE * l;
        mymax = fmaxf(mymax, l);
        mysum += eaw;
    }
#pragma unroll
    for (int o = 32; o; o >>= 1) {
        mymax = fmaxf(mymax, __shfl_xor(mymax, o));
        mysum += __shfl_xor(mysum, o);
    }
    float lself = hs[n] + hdn + mysum / fmaxf((float)deg, 1.f);
    lself = (lself >= 0.f) ? lself : SLOPE * lself;
    float m = fmaxf(mymax, lself);

    // pass 2: 8 edge-groups x 8 feature-quads
    int g = lane >> 3, q = lane & 7;
    float ax = 0.f, ay = 0.f, az = 0.f, aw = 0.f, wsum = 0.f;
    for (int j = beg + g; j < end; j += 8) {
        int2 cp = cpack[j];
        __half2 hv2 = *reinterpret_cast<__half2*>(&cp.y);
        float2 ew = __half22float2(hv2);
        float eaw = (LAYER == 0) ? ew.x : ew.y;
        int s = cp.x;
        float l = hs[s] + hdn + eaw;
        l = (l >= 0.f) ? l : SLOPE * l;
        float w = __expf(l - m);
        wsum += w;
        float hx, hy, hz, hw;
        if (LAYER == 0) {
            float x0 = hsrc[s * 3], x1 = hsrc[s * 3 + 1], x2 = hsrc[s * 3 + 2];
            int k = q * 4;
            hx = x0 * sW[k + 0] + x1 * sW[32 + k + 0] + x2 * sW[64 + k + 0];
            hy = x0 * sW[k + 1] + x1 * sW[32 + k + 1] + x2 * sW[64 + k + 1];
            hz = x0 * sW[k + 2] + x1 * sW[32 + k + 2] + x2 * sW[64 + k + 2];
            hw = x0 * sW[k + 3] + x1 * sW[32 + k + 3] + x2 * sW[64 + k + 3];
        } else {
            float4 hv4 = reinterpret_cast<const float4*>(hsrc + (size_t)s * 32)[q];
            hx = hv4.x; hy = hv4.y; hz = hv4.z; hw = hv4.w;
        }
        ax += w * hx; ay += w * hy; az += w * hz; aw += w * hw;
    }
    // implicit self-loop edge
    if (g == (deg & 7)) {
        float w = __expf(lself - m);
        wsum += w;
        float hx, hy, hz, hw;
        if (LAYER == 0) {
            float x0 = hsrc[n * 3], x1 = hsrc[n * 3 + 1], x2 = hsrc[n * 3 + 2];
            int k = q * 4;
            hx = x0 * sW[k + 0] + x1 * sW[32 + k + 0] + x2 * sW[64 + k + 0];
            hy = x0 * sW[k + 1] + x1 * sW[32 + k + 1] + x2 * sW[64 + k + 1];
            hz = x0 * sW[k + 2] + x1 * sW[32 + k + 2] + x2 * sW[64 + k + 2];
            hw = x0 * sW[k + 3] + x1 * sW[32 + k + 3] + x2 * sW[64 + k + 3];
        } else {
            float4 hv4 = reinterpret_cast<const float4*>(hsrc + (size_t)n * 32)[q];
            hx = hv4.x; hy = hv4.y; hz = hv4.z; hw = hv4.w;
        }
        ax += w * hx; ay += w * hy; az += w * hz; aw += w * hw;
    }
    // reduce across the 8 edge-groups (lanes with same q)
#pragma unroll
    for (int o = 8; o < 64; o <<= 1) {
        ax += __shfl_xor(ax, o); ay += __shfl_xor(ay, o);
        az += __shfl_xor(az, o); aw += __shfl_xor(aw, o);
        wsum += __shfl_xor(wsum, o);
    }
    float inv = 1.f / wsum;
    if (LAYER == 0) {
        if (lane < 8) {
            float4 bb = reinterpret_cast<const float4*>(bias)[q];
            float4 o4;
            o4.x = fmaxf(ax * inv + bb.x, 0.f);
            o4.y = fmaxf(ay * inv + bb.y, 0.f);
            o4.z = fmaxf(az * inv + bb.z, 0.f);
            o4.w = fmaxf(aw * inv + bb.w, 0.f);
            reinterpret_cast<float4*>(out + (size_t)n * 32)[q] = o4;
        }
    } else {
        float4 bb = reinterpret_cast<const float4*>(bias)[q];
        float4 wl = reinterpret_cast<const float4*>(Wl)[q];
        float part = (ax * inv + bb.x) * wl.x + (ay * inv + bb.y) * wl.y +
                     (az * inv + bb.z) * wl.z + (aw * inv + bb.w) * wl.w;
        part += __shfl_xor(part, 1);
        part += __shfl_xor(part, 2);
        part += __shfl_xor(part, 4);
        if (lane == 0) out[n] = fmaxf(part + bl[0], 0.f);
    }
}

extern "C" void kernel_launch(void* const* d_in, const int* in_sizes, int n_in,
                              void* d_out, int out_size, void* d_ws, size_t ws_size,
                              hipStream_t stream) {
    const float* x   = (const float*)d_in[0];
    const int*   ei  = (const int*)d_in[1];
    const float* ea  = (const float*)d_in[2];
    const float* W1  = (const float*)d_in[3];
    const float* We1 = (const float*)d_in[4];
    const float* as1 = (const float*)d_in[5];
    const float* ad1 = (const float*)d_in[6];
    const float* ae1 = (const float*)d_in[7];
    const float* b1  = (const float*)d_in[8];
    const float* W2  = (const float*)d_in[9];
    const float* We2 = (const float*)d_in[10];
    const float* as2 = (const float*)d_in[11];
    const float* ad2 = (const float*)d_in[12];
    const float* ae2 = (const float*)d_in[13];
    const float* b2  = (const float*)d_in[14];
    const float* Wl  = (const float*)d_in[15];
    const float* bl  = (const float*)d_in[16];
    float* out = (float*)d_out;

    const size_t n = NN, E = EE;
    float* ws = (float*)d_ws;
    int*   rp    = (int*)ws;                         // n+1 (pad to n+4)
    int*   deg   = (int*)ws + n + 4;                 // n
    int*   cur   = (int*)ws + 2 * n + 4;             // n
    int*   loc   = (int*)ws + 3 * n + 4;             // n
    int*   bsum  = (int*)ws + 4 * n + 4;             // 128
    float* hs    = ws + 4 * n + 132;                 // n
    float* hd    = ws + 5 * n + 132;                 // n
    float* sml   = ws + 6 * n + 132;                 // 16
    int2*  cpack = (int2*)(ws + 6 * n + 148);        // E (8B each)
    float* h     = ws + 6 * n + 148 + 2 * E;         // 32n
    float* xbuf  = ws + 38 * n + 148 + 2 * E;        // 32n

    dim3 b256(256);
    int gE  = (EE + 255) / 256;
    int gN  = (NN + 255) / 256;
    int gN1 = (NN + 256) / 256;   // covers NN+1
    int gG  = (NN * 64 + 255) / 256;

    // CSR build
    hipMemsetAsync(deg, 0, n * sizeof(int), stream);
    k_small<<<1, 64, 0, stream>>>(We1, ae1, We2, ae2, W1, as1, ad1, sml);
    k_deg<<<gE, b256, 0, stream>>>(ei, deg);
    k_scan1<<<SNB, SB, 0, stream>>>(deg, loc, bsum);
    k_scan2<<<1, 128, 0, stream>>>(bsum);
    k_scan3<<<gN1, b256, 0, stream>>>(loc, bsum, rp, cur, x, sml, hs, hd);
    k_scatter<<<SGRID, b256, 0, stream>>>(ei, ea, sml, cur, cpack);

    // layer 1 (h1 recomputed on the fly from x)
    k_gather<0><<<gG, b256, 0, stream>>>(rp, cpack, x, W1, hs, hd, b1,
                                         nullptr, nullptr, xbuf);

    // layer 2 (+ fused final linear + relu)
    k_h2<<<gN, b256, 0, stream>>>(xbuf, W2, as2, ad2, h, hs, hd);
    k_gather<1><<<gG, b256, 0, stream>>>(rp, cpack, h, nullptr, hs, hd, b2,
                                         Wl, bl, out);
}